// Round 9
// baseline (945.539 us; speedup 1.0000x reference)
//
#include <hip/hip_runtime.h>
#include <math.h>

typedef __attribute__((ext_vector_type(8))) short bf16x8;
typedef __attribute__((ext_vector_type(4))) float f32x4;
typedef unsigned short u16;
typedef unsigned int u32;

#define DEV static __device__ __forceinline__

typedef __attribute__((address_space(3))) u32 lds_u32;
typedef const __attribute__((address_space(1))) u32 glb_u32;

DEV void gload16(const void* g, void* l){
  __builtin_amdgcn_global_load_lds((glb_u32*)g, (lds_u32*)l, 16, 0, 0);
}

DEV u16 f2bf(float f){
  u32 u = __builtin_bit_cast(u32, f);
  u32 r = (u + 0x7fffu + ((u >> 16) & 1u)) >> 16;
  return (u16)r;
}
DEV float bf2f(u16 h){
  u32 u = ((u32)h) << 16;
  return __builtin_bit_cast(float, u);
}
DEV u32 cvtpk(float a, float b){
  u32 r;
  asm("v_cvt_pk_bf16_f32 %0, %1, %2" : "=v"(r) : "v"(a), "v"(b));
  return r;
}
DEV float gelu_exact(float x){ return 0.5f*x*(1.f+erff(x*0.70710678118654752f)); }

#define QSCALE 0.18033688f   /* 0.125 * log2(e) */

DEV void xcd_remap(int &bx, int &by){
  int gx = gridDim.x, gy = gridDim.y;
  int n = gx*gy;
  if ((n & 7) == 0){
    int id = by*gx + bx;
    int q = n >> 3;
    int sid = (id & 7)*q + (id >> 3);
    bx = sid % gx;
    by = sid / gx;
  }
}

// ---------------- elementwise ----------------
__global__ __launch_bounds__(256) void k_copy_f32(const float* __restrict__ in, float* __restrict__ out, int n4){
  int i = blockIdx.x*256 + threadIdx.x;
  if (i < n4) ((float4*)out)[i] = ((const float4*)in)[i];
}

__global__ __launch_bounds__(256) void k_cvt_bf16(const float* __restrict__ in, u16* __restrict__ out, int n4){
  int i = blockIdx.x*256 + threadIdx.x;
  if (i < n4){
    float4 v = ((const float4*)in)[i];
    ushort4 o;
    o.x = f2bf(v.x); o.y = f2bf(v.y); o.z = f2bf(v.z); o.w = f2bf(v.w);
    ((ushort4*)out)[i] = o;
  }
}

struct CvtArgs { const float4* s[16]; ushort4* d[16]; };
__global__ __launch_bounds__(256) void k_cvt_all(CvtArgs a){
  int i = blockIdx.x*256 + threadIdx.x;
  int seg = i >> 19;
  int off = i & 0x7FFFF;
  float4 v = a.s[seg][off];
  ushort4 o;
  o.x = f2bf(v.x); o.y = f2bf(v.y); o.z = f2bf(v.z); o.w = f2bf(v.w);
  a.d[seg][off] = o;
}

__global__ __launch_bounds__(256) void k_trig(const float* __restrict__ rope,
    float2* __restrict__ ctq, float2* __restrict__ ctk){
  int i = blockIdx.x*256 + threadIdx.x;
  int d = i & 63;
  float a = rope[i];
  float c = cosf(a), s = sinf(a);
  float sg = (d < 32) ? -s : s;
  ctk[i] = make_float2(c, sg);
  ctq[i] = make_float2(c*QSCALE, sg*QSCALE);
}

__global__ __launch_bounds__(256) void k_ada(const float* __restrict__ te,
    const float* __restrict__ adaW, const float* __restrict__ adab,
    float* __restrict__ mods){
  int row = blockIdx.x*4 + (threadIdx.x>>6);
  int lane = threadIdx.x & 63;
  const float* wr = adaW + (size_t)row*1024;
  float s = 0.f;
  #pragma unroll
  for (int j=0; j<4; j++){
    int c = lane*4 + j*256;
    float4 a = *(const float4*)(te + c);
    float4 b = *(const float4*)(wr + c);
    s += a.x*b.x + a.y*b.y + a.z*b.z + a.w*b.w;
  }
  #pragma unroll
  for (int off=32; off; off>>=1) s += __shfl_down(s, off);
  if (!lane) mods[row] = s + adab[row];
}

__global__ __launch_bounds__(256) void k_ln_mod(const float* __restrict__ x,
    const float* __restrict__ sh, const float* __restrict__ sc,
    u16* __restrict__ out){
  int row = blockIdx.x, t = threadIdx.x;
  const float* xr = x + (size_t)row*1024;
  float4 v = ((const float4*)xr)[t];
  float s  = v.x+v.y+v.z+v.w;
  float sq = v.x*v.x+v.y*v.y+v.z*v.z+v.w*v.w;
  #pragma unroll
  for (int off=32; off; off>>=1){ s += __shfl_down(s,off); sq += __shfl_down(sq,off); }
  __shared__ float red[8];
  int w = t>>6, lane = t&63;
  if (!lane){ red[w] = s; red[4+w] = sq; }
  __syncthreads();
  s  = red[0]+red[1]+red[2]+red[3];
  sq = red[4]+red[5]+red[6]+red[7];
  float mean = s*(1.f/1024.f);
  float var  = sq*(1.f/1024.f) - mean*mean;
  float rst  = rsqrtf(var + 1e-6f);
  float vv[4] = {v.x, v.y, v.z, v.w};
  ushort4 o;
  u16 ob[4];
  #pragma unroll
  for (int j=0;j<4;j++){
    int col = t*4+j;
    float y = (vv[j]-mean)*rst;
    if (sh) y = y*(1.f + sc[col]) + sh[col];
    ob[j] = f2bf(y);
  }
  o.x=ob[0]; o.y=ob[1]; o.z=ob[2]; o.w=ob[3];
  *(ushort4*)(out + (size_t)row*1024 + t*4) = o;
}

// RoPE in-place (fallback path only)
__global__ __launch_bounds__(256) void k_rope(u16* __restrict__ q, u16* __restrict__ k,
    const float* __restrict__ rope){
  int idx = blockIdx.x*256 + threadIdx.x;
  int d = idx & 31;
  int h = (idx >> 5) & 15;
  int p = idx >> 9;
  const float* rr = rope + (size_t)p*64;
  float a0 = rr[d], a1 = rr[d+32];
  float c0 = cosf(a0), s0 = sinf(a0);
  float c1 = cosf(a1), s1 = sinf(a1);
  size_t o = (size_t)p*1024 + h*64 + d;
  float q0 = bf2f(q[o]), q1 = bf2f(q[o+32]);
  q[o]    = f2bf((q0*c0 - q1*s0)*QSCALE);
  q[o+32] = f2bf((q1*c1 + q0*s1)*QSCALE);
  float k0 = bf2f(k[o]), k1 = bf2f(k[o+32]);
  k[o]    = f2bf(k0*c0 - k1*s0);
  k[o+32] = f2bf(k1*c1 + k0*s1);
}

// ---------------- shared GEMM mainloop (bf16 W, dbuf + prefetch) ----------------
DEV void gemm_loop(const u16* __restrict__ X, const u16* __restrict__ W,
                   int bm, int bn, int ld, int lenK, u16* As, u16* Bs, f32x4 acc[4][4])
{
  int t = threadIdx.x;
  int w = t>>6, lane = t&63;
  int wr = (w>>1)*64, wc = (w&1)*64;
  int fr = lane&15, g = lane>>4;
  int arow = lane>>2, acol = (lane&3)*8;
  const u16* xp = X + (size_t)(bm + w*32 + arow)*ld + acol;
  const u16* wp = W + (size_t)(bn + w*32 + arow)*ld + acol;
  int nk = lenK >> 5;
  {
    u16* a = As + w*1024; u16* b = Bs + w*1024;
    gload16(xp, a);             gload16(xp + (size_t)16*ld, a + 512);
    gload16(wp, b);             gload16(wp + (size_t)16*ld, b + 512);
  }
  for (int kt = 0; kt < nk; ++kt){
    __syncthreads();
    int cur = kt & 1;
    if (kt + 1 < nk){
      int nb = cur ^ 1;
      int k0 = (kt+1) << 5;
      u16* a = As + nb*4096 + w*1024; u16* b = Bs + nb*4096 + w*1024;
      gload16(xp + k0, a);        gload16(xp + k0 + (size_t)16*ld, a + 512);
      gload16(wp + k0, b);        gload16(wp + k0 + (size_t)16*ld, b + 512);
    }
    const u16* ab = As + cur*4096;
    const u16* bb = Bs + cur*4096;
    bf16x8 a[4], b[4];
    #pragma unroll
    for (int i=0;i<4;i++) a[i] = *(const bf16x8*)(ab + (wr+i*16+fr)*32 + g*8);
    #pragma unroll
    for (int i=0;i<4;i++) b[i] = *(const bf16x8*)(bb + (wc+i*16+fr)*32 + g*8);
    __builtin_amdgcn_s_setprio(1);
    #pragma unroll
    for (int i=0;i<4;i++)
      #pragma unroll
      for (int j=0;j<4;j++)
        acc[i][j] = __builtin_amdgcn_mfma_f32_16x16x32_bf16(a[i], b[j], acc[i][j], 0, 0, 0);
    __builtin_amdgcn_s_setprio(0);
  }
}

// ---------------- standalone GEMM (bf16 W): EPI 1 gelu, 2 gated-residual, 4 scaled ----------------
template<int EPI>
__global__ __launch_bounds__(256) void k_gemm_bf16(
    const u16* __restrict__ X, const u16* __restrict__ W,
    const float* __restrict__ bias,
    u16* __restrict__ Yout,
    const float* __restrict__ resin, float* __restrict__ resout,
    const float* __restrict__ gate,
    int M, int N, int K)
{
  __shared__ __align__(16) u16 As[2*128*32];
  __shared__ __align__(16) u16 Bs[2*128*32];
  int bx = blockIdx.x, by = blockIdx.y;
  xcd_remap(bx, by);
  int bm = bx*128, bn = by*128;
  f32x4 acc[4][4] = {};
  gemm_loop(X, W, bm, bn, K, K, As, Bs, acc);
  int lane = threadIdx.x & 63, w = threadIdx.x>>6;
  int wr = (w>>1)*64, wc = (w&1)*64;
  int fr = lane&15, g = lane>>4;
  #pragma unroll
  for (int i=0;i<4;i++){
    #pragma unroll
    for (int j=0;j<4;j++){
      int col = bn + wc + j*16 + fr;
      float bv = bias ? bias[col] : 0.f;
      #pragma unroll
      for (int r=0;r<4;r++){
        int row = bm + wr + i*16 + g*4 + r;
        float y = acc[i][j][r] + bv;
        if (EPI == 1){
          Yout[(size_t)row*N + col] = f2bf(gelu_exact(y));
        } else if (EPI == 2){
          float gt = gate ? gate[col] : 1.f;
          resout[(size_t)row*N + col] = resin[(size_t)row*N + col] + gt*y;
        } else {
          Yout[(size_t)row*N + col] = f2bf(y*QSCALE);
        }
      }
    }
  }
}

// ---------------- split-K partial GEMM ----------------
__global__ __launch_bounds__(256) void k_gemm_part(
    const u16* __restrict__ X, const u16* __restrict__ W,
    float* __restrict__ pp, int M, int N, int K, int Ks)
{
  __shared__ __align__(16) u16 As[2*128*32];
  __shared__ __align__(16) u16 Bs[2*128*32];
  int bx = blockIdx.x, by = blockIdx.y;
  xcd_remap(bx, by);
  int s = blockIdx.z;
  int bm = bx*128, bn = by*128;
  f32x4 acc[4][4] = {};
  gemm_loop(X + (size_t)s*Ks, W + (size_t)s*Ks, bm, bn, K, Ks, As, Bs, acc);
  float* out = pp + (size_t)s*M*N;
  int lane = threadIdx.x & 63, w = threadIdx.x>>6;
  int wr = (w>>1)*64, wc = (w&1)*64;
  int fr = lane&15, g = lane>>4;
  #pragma unroll
  for (int i=0;i<4;i++)
    #pragma unroll
    for (int j=0;j<4;j++){
      int col = bn + wc + j*16 + fr;
      #pragma unroll
      for (int r=0;r<4;r++){
        int row = bm + wr + i*16 + g*4 + r;
        out[(size_t)row*N + col] = acc[i][j][r];
      }
    }
}

// ---------------- split-K reduce ----------------
template<int EPI>
__global__ __launch_bounds__(256) void k_reduce(
    const float* __restrict__ pp, int S, const float* __restrict__ bias,
    const float* __restrict__ resin, float* __restrict__ resout,
    const float* __restrict__ gate, u16* __restrict__ Ybf,
    int MN, int N)
{
  int idx = blockIdx.x*256 + threadIdx.x;
  int base = idx*4;
  if (base >= MN) return;
  float4 s4 = *(const float4*)(pp + base);
  for (int s=1; s<S; ++s){
    float4 t4 = *(const float4*)(pp + (size_t)s*MN + base);
    s4.x += t4.x; s4.y += t4.y; s4.z += t4.z; s4.w += t4.w;
  }
  int col = base & (N-1);
  float b0=0,b1=0,b2=0,b3=0;
  if (bias){ b0=bias[col]; b1=bias[col+1]; b2=bias[col+2]; b3=bias[col+3]; }
  if (EPI == 2){
    float g0=1,g1=1,g2=1,g3=1;
    if (gate){ g0=gate[col]; g1=gate[col+1]; g2=gate[col+2]; g3=gate[col+3]; }
    float4 rv = *(const float4*)(resin + base);
    float4 o;
    o.x = rv.x + g0*(s4.x+b0);
    o.y = rv.y + g1*(s4.y+b1);
    o.z = rv.z + g2*(s4.z+b2);
    o.w = rv.w + g3*(s4.w+b3);
    *(float4*)(resout + base) = o;
  } else {
    ushort4 o;
    o.x = f2bf((s4.x+b0)*QSCALE);
    o.y = f2bf((s4.y+b1)*QSCALE);
    o.z = f2bf((s4.z+b2)*QSCALE);
    o.w = f2bf((s4.w+b3)*QSCALE);
    *(ushort4*)(Ybf + base) = o;
  }
}

// ---------------- fused split-K reduce + residual + LayerNorm ----------------
template<int MOD>
__global__ __launch_bounds__(256) void k_reduce_ln(
    const float* __restrict__ pp, int S, const float* __restrict__ bias,
    const float* __restrict__ resin, float* __restrict__ resout,
    const float* __restrict__ gate,
    const float* __restrict__ sh, const float* __restrict__ sc,
    u16* __restrict__ hx)
{
  int row = blockIdx.x, t = threadIdx.x;
  size_t base = (size_t)row*1024 + t*4;
  const size_t MN = (size_t)3072*1024;
  float4 s4 = *(const float4*)(pp + base);
  for (int s=1; s<S; ++s){
    float4 t4 = *(const float4*)(pp + (size_t)s*MN + base);
    s4.x += t4.x; s4.y += t4.y; s4.z += t4.z; s4.w += t4.w;
  }
  int col = t*4;
  float b0=0,b1=0,b2=0,b3=0;
  if (bias){ b0=bias[col]; b1=bias[col+1]; b2=bias[col+2]; b3=bias[col+3]; }
  float g0=1,g1=1,g2=1,g3=1;
  if (gate){ g0=gate[col]; g1=gate[col+1]; g2=gate[col+2]; g3=gate[col+3]; }
  float4 rv = *(const float4*)(resin + base);
  float y[4];
  y[0] = rv.x + g0*(s4.x+b0);
  y[1] = rv.y + g1*(s4.y+b1);
  y[2] = rv.z + g2*(s4.z+b2);
  y[3] = rv.w + g3*(s4.w+b3);
  float4 ov; ov.x=y[0]; ov.y=y[1]; ov.z=y[2]; ov.w=y[3];
  *(float4*)(resout + base) = ov;
  float s  = y[0]+y[1]+y[2]+y[3];
  float sq = y[0]*y[0]+y[1]*y[1]+y[2]*y[2]+y[3]*y[3];
  #pragma unroll
  for (int off=32; off; off>>=1){ s += __shfl_down(s,off); sq += __shfl_down(sq,off); }
  __shared__ float red[8];
  int w = t>>6, lane = t&63;
  if (!lane){ red[w] = s; red[4+w] = sq; }
  __syncthreads();
  s  = red[0]+red[1]+red[2]+red[3];
  sq = red[4]+red[5]+red[6]+red[7];
  float mean = s*(1.f/1024.f);
  float var  = sq*(1.f/1024.f) - mean*mean;
  float rst  = rsqrtf(var + 1e-6f);
  ushort4 o;
  u16 ob[4];
  #pragma unroll
  for (int j=0;j<4;j++){
    float yy = (y[j]-mean)*rst;
    if (MOD) yy = yy*(1.f + sc[col+j]) + sh[col+j];
    ob[j] = f2bf(yy);
  }
  o.x=ob[0]; o.y=ob[1]; o.z=ob[2]; o.w=ob[3];
  *(ushort4*)(hx + base) = o;
}

// ---------------- fused QKV GEMM (+ fused rope on q,k) ----------------
template<int MODE>
__global__ __launch_bounds__(256) void k_qkv(
    const u16* __restrict__ X,
    const u16* __restrict__ W0, const u16* __restrict__ W1, const u16* __restrict__ W2,
    u16* __restrict__ Y0, u16* __restrict__ Y1, u16* __restrict__ VT,
    const float2* __restrict__ ctq, const float2* __restrict__ ctk,
    int M, int ldvt)
{
  __shared__ __align__(16) u16 As[2*128*32];
  __shared__ __align__(16) u16 Bs[2*128*32];
  int bx = blockIdx.x, by = blockIdx.y;
  xcd_remap(bx, by);
  int bm = bx*128, bn = by*128;
  int sel = bn >> 10;
  int bnl = bn & 1023;
  const u16* W = (sel==0 ? W0 : (sel==1 ? W1 : W2));
  f32x4 acc[4][4] = {};
  gemm_loop(X, W, bm, bnl, 1024, 1024, As, Bs, acc);
  int lane = threadIdx.x & 63, w = threadIdx.x>>6;
  int wr = (w>>1)*64, wc = (w&1)*64;
  int fr = lane&15, g = lane>>4;
  if (sel < 2){
    u16* Y = (sel==0) ? Y0 : Y1;
    const float2* ct = (sel==0) ? ctq : ctk;
    #pragma unroll
    for (int i=0;i<4;i++)
      #pragma unroll
      for (int j=0;j<4;j++){
        int col = bnl + wc + j*16 + fr;
        int d = j*16 + fr;
        #pragma unroll
        for (int r=0;r<4;r++){
          int row = bm + wr + i*16 + g*4 + r;
          float2 cs = ct[row*64 + d];
          float yv = acc[i][j][r]*cs.x + acc[i][j^2][r]*cs.y;
          Y[(size_t)row*1024 + col] = f2bf(yv);
        }
      }
  } else {
    #pragma unroll
    for (int i=0;i<4;i++)
      #pragma unroll
      for (int j=0;j<4;j++){
        int col = bnl + wc + j*16 + fr;
        int row0 = bm + wr + i*16 + g*4;
        uint2 pk;
        pk.x = cvtpk(acc[i][j][0], acc[i][j][1]);
        pk.y = cvtpk(acc[i][j][2], acc[i][j][3]);
        *(uint2*)(VT + (size_t)col*ldvt + row0) = pk;
      }
  }
}

// ---------------- cross K/V GEMM: 64x64 tiles, grid (8,32)=256 balanced ----------------
__global__ __launch_bounds__(256) void k_kv64(
    const u16* __restrict__ X,
    const u16* __restrict__ Wk, const u16* __restrict__ Wv,
    u16* __restrict__ Kout, u16* __restrict__ VTout, int ldvt)
{
  __shared__ __align__(16) u16 As[2*64*32];
  __shared__ __align__(16) u16 Bs[2*64*32];
  int bx = blockIdx.x, by = blockIdx.y;
  xcd_remap(bx, by);
  int bm = bx*64;
  int sel = by >> 4;
  int bnl = (by & 15)*64;
  const u16* W = sel ? Wv : Wk;
  int t = threadIdx.x, w = t>>6, lane = t&63;
  int wr = (w>>1)*32, wc = (w&1)*32;
  int fr = lane&15, g = lane>>4;
  f32x4 acc[2][2] = {};
  int arow = lane>>2, acol = (lane&3)*8;
  const u16* xp = X + (size_t)(bm + w*16 + arow)*1024 + acol;
  const u16* wp = W + (size_t)(bnl + w*16 + arow)*1024 + acol;
  {
    gload16(xp, As + w*512);
    gload16(wp, Bs + w*512);
  }
  for (int kt = 0; kt < 32; ++kt){
    __syncthreads();
    int cur = kt & 1;
    if (kt + 1 < 32){
      int nb = cur ^ 1;
      int k0 = (kt+1) << 5;
      gload16(xp + k0, As + nb*2048 + w*512);
      gload16(wp + k0, Bs + nb*2048 + w*512);
    }
    const u16* ab = As + cur*2048;
    const u16* bb = Bs + cur*2048;
    bf16x8 a[2], b[2];
    #pragma unroll
    for (int i=0;i<2;i++) a[i] = *(const bf16x8*)(ab + (wr+i*16+fr)*32 + g*8);
    #pragma unroll
    for (int i=0;i<2;i++) b[i] = *(const bf16x8*)(bb + (wc+i*16+fr)*32 + g*8);
    __builtin_amdgcn_s_setprio(1);
    #pragma unroll
    for (int i=0;i<2;i++)
      #pragma unroll
      for (int j=0;j<2;j++)
        acc[i][j] = __builtin_amdgcn_mfma_f32_16x16x32_bf16(a[i], b[j], acc[i][j], 0, 0, 0);
    __builtin_amdgcn_s_setprio(0);
  }
  #pragma unroll
  for (int i=0;i<2;i++)
    #pragma unroll
    for (int j=0;j<2;j++){
      int col = bnl + wc + j*16 + fr;
      if (sel == 0){
        #pragma unroll
        for (int r=0;r<4;r++){
          int row = bm + wr + i*16 + g*4 + r;
          Kout[(size_t)row*1024 + col] = f2bf(acc[i][j][r]);
        }
      } else {
        int row0 = bm + wr + i*16 + g*4;
        uint2 pk;
        pk.x = cvtpk(acc[i][j][0], acc[i][j][1]);
        pk.y = cvtpk(acc[i][j][2], acc[i][j][3]);
        *(uint2*)(VTout + (size_t)col*ldvt + row0) = pk;
      }
    }
}

// ---------------- fallback GEMM (f32 weights in-flight) ----------------
template<int EPI>
__global__ __launch_bounds__(256) void k_gemm_f32(
    const u16* __restrict__ X, const float* __restrict__ W,
    const float* __restrict__ bias,
    u16* __restrict__ Yout,
    const float* __restrict__ resin, float* __restrict__ resout,
    const float* __restrict__ gate,
    int M, int N, int K)
{
  __shared__ __align__(16) u16 As[128][32];
  __shared__ __align__(16) u16 Bs[128][40];
  int bx = blockIdx.x, by = blockIdx.y;
  xcd_remap(bx, by);
  int bm = bx*128, bn = by*128;
  int t = threadIdx.x;
  int w = t>>6, lane = t&63;
  int wr = (w>>1)*64, wc = (w&1)*64;
  int fr = lane&15, g = lane>>4;
  f32x4 acc[4][4] = {};
  int arow = lane>>2, acol = (lane&3)*8;
  int srow = t>>2, scol = (t&3)*8;
  for (int k0=0; k0<K; k0+=32){
    #pragma unroll
    for (int inst=0; inst<2; ++inst){
      int r = w*32 + inst*16 + arow;
      gload16(X + (size_t)(bm+r)*K + k0 + acol, &As[w*32+inst*16][0]);
    }
    #pragma unroll
    for (int it=0; it<2; ++it){
      const float* wp = W + (size_t)(bn+srow+it*64)*K + k0 + scol;
      float4 f0 = *(const float4*)(wp);
      float4 f1 = *(const float4*)(wp+4);
      uint4 bw;
      bw.x = (u32)f2bf(f0.x) | ((u32)f2bf(f0.y)<<16);
      bw.y = (u32)f2bf(f0.z) | ((u32)f2bf(f0.w)<<16);
      bw.z = (u32)f2bf(f1.x) | ((u32)f2bf(f1.y)<<16);
      bw.w = (u32)f2bf(f1.z) | ((u32)f2bf(f1.w)<<16);
      *(uint4*)&Bs[srow+it*64][scol] = bw;
    }
    __syncthreads();
    bf16x8 a[4], b[4];
    #pragma unroll
    for (int i=0;i<4;i++) a[i] = *(const bf16x8*)&As[wr+i*16+fr][g*8];
    #pragma unroll
    for (int i=0;i<4;i++) b[i] = *(const bf16x8*)&Bs[wc+i*16+fr][g*8];
    #pragma unroll
    for (int i=0;i<4;i++)
      #pragma unroll
      for (int j=0;j<4;j++)
        acc[i][j] = __builtin_amdgcn_mfma_f32_16x16x32_bf16(a[i], b[j], acc[i][j], 0, 0, 0);
    __syncthreads();
  }
  #pragma unroll
  for (int i=0;i<4;i++){
    #pragma unroll
    for (int j=0;j<4;j++){
      int col = bn + wc + j*16 + fr;
      float bv = bias ? bias[col] : 0.f;
      #pragma unroll
      for (int r=0;r<4;r++){
        int row = bm + wr + i*16 + g*4 + r;
        float y = acc[i][j][r] + bv;
        if (EPI == 0){
          Yout[(size_t)row*N + col] = f2bf(y);
        } else if (EPI == 1){
          Yout[(size_t)row*N + col] = f2bf(gelu_exact(y));
        } else if (EPI == 2){
          float gt = gate ? gate[col] : 1.f;
          resout[(size_t)row*N + col] = resin[(size_t)row*N + col] + gt*y;
        } else if (EPI == 3){
          Yout[(size_t)col*M + row] = f2bf(y);
        } else {
          Yout[(size_t)row*N + col] = f2bf(y*QSCALE);
        }
      }
    }
  }
}

// ---------------- Flash attention: R6 structure + V direct-to-register ----------------
// K staged via global_load_lds (swizzled); V read straight from VT (contiguous
// 16B per lane, L2-resident). Per tile/wave LDS reads drop 18->10 b128.
__global__ __launch_bounds__(256) void k_flash(
    const u16* __restrict__ Q, const u16* __restrict__ Kb, const u16* __restrict__ VT,
    u16* __restrict__ O, int Lkv)
{
  __shared__ __align__(16) u16 Ks[2*64*64];
  __shared__ __align__(16) u16 Ps[4][16][72];
  int bx = blockIdx.x, by = blockIdx.y;
  xcd_remap(bx, by);
  int h = by;
  int q0 = bx*64;
  int t = threadIdx.x, w = t>>6, lane = t&63;
  int fr = lane&15, g = lane>>4;
  const u16* qrow = Q + (size_t)(q0 + w*16 + fr)*1024 + h*64;
  bf16x8 aq0 = *(const bf16x8*)(qrow + g*8);
  bf16x8 aq1 = *(const bf16x8*)(qrow + 32 + g*8);
  f32x4 accO[4] = {};
  float l = 0.f;
  int slot = lane & 7, rop = lane >> 3;
  const u16* kbase = Kb + (size_t)h*64;
  const u16* vbase = VT + (size_t)h*64*Lkv;
  int nt = Lkv >> 6;
  auto stage = [&](int tt){
    int buf = tt & 1;
    int k0 = tt << 6;
    #pragma unroll
    for (int inst=0; inst<2; ++inst){
      int row = w*16 + inst*8 + rop;
      int ss = slot ^ (row & 7);
      gload16(kbase + (size_t)(k0+row)*1024 + ss*8, Ks + buf*4096 + row*64);
    }
  };
  stage(0);
  for (int tt=0; tt<nt; ++tt){
    __syncthreads();
    int cur = tt & 1;
    const u16* kc = Ks + cur*4096;
    int k0 = tt << 6;
    // V fragments direct from global (issued first so later waits keep prefetch alive)
    bf16x8 vb0[4], vb1[4];
    #pragma unroll
    for (int nd=0; nd<4; nd++){
      const u16* vrow = vbase + (size_t)(nd*16 + fr)*Lkv + k0;
      vb0[nd] = *(const bf16x8*)(vrow + g*8);
      vb1[nd] = *(const bf16x8*)(vrow + 32 + g*8);
    }
    if (tt+1 < nt) stage(tt+1);
    // S^T = K.Q^T : lane holds S[kv=kb*16+g*4+r][q=fr]
    f32x4 st[4] = {};
    __builtin_amdgcn_s_setprio(1);
    #pragma unroll
    for (int kb=0;kb<4;kb++){
      int rowK = kb*16 + fr;
      bf16x8 b0 = *(const bf16x8*)(kc + rowK*64 + ((g  ) ^ (rowK&7))*8);
      bf16x8 b1 = *(const bf16x8*)(kc + rowK*64 + ((4+g) ^ (rowK&7))*8);
      st[kb] = __builtin_amdgcn_mfma_f32_16x16x32_bf16(b0, aq0, st[kb], 0,0,0);
      st[kb] = __builtin_amdgcn_mfma_f32_16x16x32_bf16(b1, aq1, st[kb], 0,0,0);
    }
    __builtin_amdgcn_s_setprio(0);
    float ts = 0.f;
    u32 pk[8];
    #pragma unroll
    for (int kb=0;kb<4;kb++){
      float p0 = exp2f(st[kb][0]);
      float p1 = exp2f(st[kb][1]);
      float p2 = exp2f(st[kb][2]);
      float p3 = exp2f(st[kb][3]);
      ts += (p0+p1)+(p2+p3);
      pk[kb*2]   = cvtpk(p0,p1);
      pk[kb*2+1] = cvtpk(p2,p3);
    }
    ts += __shfl_xor(ts, 16);
    ts += __shfl_xor(ts, 32);
    l += ts;
    #pragma unroll
    for (int kb=0;kb<4;kb++){
      uint2 pv; pv.x = pk[kb*2]; pv.y = pk[kb*2+1];
      *(uint2*)&Ps[w][fr][kb*16 + g*4] = pv;
    }
    bf16x8 ap0 = *(const bf16x8*)&Ps[w][fr][g*8];
    bf16x8 ap1 = *(const bf16x8*)&Ps[w][fr][32 + g*8];
    __builtin_amdgcn_s_setprio(1);
    #pragma unroll
    for (int nd=0; nd<4; nd++){
      accO[nd] = __builtin_amdgcn_mfma_f32_16x16x32_bf16(ap0, vb0[nd], accO[nd], 0,0,0);
      accO[nd] = __builtin_amdgcn_mfma_f32_16x16x32_bf16(ap1, vb1[nd], accO[nd], 0,0,0);
    }
    __builtin_amdgcn_s_setprio(0);
  }
  float rl = 1.f / l;
  #pragma unroll
  for (int r=0;r<4;r++){
    float rlq = __shfl(rl, g*4+r);
    int row = q0 + w*16 + g*4 + r;
    #pragma unroll
    for (int nd=0; nd<4; nd++)
      O[(size_t)row*1024 + h*64 + nd*16 + fr] = f2bf(accO[nd][r] * rlq);
  }
}

// ---------------- launch ----------------
extern "C" void kernel_launch(void* const* d_in, const int* in_sizes, int n_in,
                              void* d_out, int out_size, void* d_ws, size_t ws_size,
                              hipStream_t stream){
  const float* x_in = (const float*)d_in[0];
  const float* te   = (const float*)d_in[1];
  const float* ctx  = (const float*)d_in[2];
  const float* rope = (const float*)d_in[3];
  const float* adaW = (const float*)d_in[4];
  const float* adab = (const float*)d_in[5];
  const float* sqW  = (const float*)d_in[6];
  const float* skW  = (const float*)d_in[7];
  const float* svW  = (const float*)d_in[8];
  const float* soW  = (const float*)d_in[9];
  const float* sob  = (const float*)d_in[10];
  const float* cqW  = (const float*)d_in[11];
  const float* ckW  = (const float*)d_in[12];
  const float* cvW  = (const float*)d_in[13];
  const float* coW  = (const float*)d_in[14];
  const float* cob  = (const float*)d_in[15];
  const float* f1W  = (const float*)d_in[16];
  const float* f1b  = (const float*)d_in[17];
  const float* f2W  = (const float*)d_in[18];
  const float* f2b  = (const float*)d_in[19];
  float* x = (float*)d_out;

  char* p = (char*)d_ws;
  size_t used = 0;
  auto alloc = [&](size_t bytes){
    void* r = (void*)(p + used);
    used += (bytes + 255) & ~(size_t)255;
    return r;
  };
  u16* hx   = (u16*)alloc((size_t)3072*1024*2);
  u16* qb   = (u16*)alloc((size_t)3072*1024*2);
  u16* kb   = (u16*)alloc((size_t)3072*1024*2);
  u16* vt   = (u16*)alloc((size_t)1024*3072*2);
  u16* ob   = (u16*)alloc((size_t)3072*1024*2);
  u16* mid  = (u16*)alloc((size_t)3072*4096*2);
  u16* ctxb = (u16*)alloc((size_t)512*1024*2);
  float* mods = (float*)alloc((size_t)2*6144*4);
  float2* ctq = (float2*)alloc((size_t)3072*64*8);
  float2* ctk = (float2*)alloc((size_t)3072*64*8);
  size_t base_used = used;
  const size_t NW_SMALL = (size_t)2*1024*1024;
  const size_t NW_BIG   = (size_t)2*4096*1024;
  size_t wbytes = (8*NW_SMALL + 2*NW_BIG)*2;
  bool pre = (base_used + wbytes + 4096) <= ws_size;

  u16 *sqWb=nullptr,*skWb=nullptr,*svWb=nullptr,*soWb=nullptr,
      *cqWb=nullptr,*ckWb=nullptr,*cvWb=nullptr,*coWb=nullptr,
      *f1Wb=nullptr,*f2Wb=nullptr;
  if (pre){
    sqWb=(u16*)alloc(NW_SMALL*2); skWb=(u16*)alloc(NW_SMALL*2);
    svWb=(u16*)alloc(NW_SMALL*2); soWb=(u16*)alloc(NW_SMALL*2);
    cqWb=(u16*)alloc(NW_SMALL*2); ckWb=(u16*)alloc(NW_SMALL*2);
    cvWb=(u16*)alloc(NW_SMALL*2); coWb=(u16*)alloc(NW_SMALL*2);
    f1Wb=(u16*)alloc(NW_BIG*2);   f2Wb=(u16*)alloc(NW_BIG*2);
  }
  const size_t PPN = (size_t)4*3072*1024;
  float* pp = nullptr;
  bool splitok = pre && (used + PPN*4 + 4096) <= ws_size;
  if (splitok) pp = (float*)alloc(PPN*4);
  const int MN = 3072*1024;

  if (pre){
    CvtArgs ca;
    const float* smallW[8] = {sqW,skW,svW,soW,cqW,ckW,cvW,coW};
    u16* smallD[8] = {sqWb,skWb,svWb,soWb,cqWb,ckWb,cvWb,coWb};
    for (int s=0; s<8; ++s){ ca.s[s] = (const float4*)smallW[s]; ca.d[s] = (ushort4*)smallD[s]; }
    for (int qd=0; qd<4; ++qd){
      ca.s[8+qd]  = (const float4*)f1W + (size_t)qd*524288;
      ca.d[8+qd]  = (ushort4*)f1Wb + (size_t)qd*524288;
      ca.s[12+qd] = (const float4*)f2W + (size_t)qd*524288;
      ca.d[12+qd] = (ushort4*)f2Wb + (size_t)qd*524288;
    }
    k_cvt_all<<<32768, 256, 0, stream>>>(ca);
  }
  k_cvt_bf16<<<512, 256, 0, stream>>>(ctx, ctxb, 131072);
  k_ada<<<3072, 256, 0, stream>>>(te, adaW, adab, mods);
  k_trig<<<768, 256, 0, stream>>>(rope, ctq, ctk);
  if (!splitok) k_copy_f32<<<3072, 256, 0, stream>>>(x_in, x, 786432);

  for (int i=0; i<2; ++i){
    const float* mi  = mods + (size_t)i*6144;
    const float* mi2 = mods + 6144;
    size_t wo = (size_t)i*1024*1024;
    size_t wof = (size_t)i*4096*1024;
    // --- self attention ---
    if (i == 0 || !splitok)
      k_ln_mod<<<3072,256,0,stream>>>(i==0 ? x_in : x, mi+0, mi+1024, hx);
    if (pre){
      k_qkv<0><<<dim3(24,24),256,0,stream>>>(hx, sqWb+wo, skWb+wo, svWb+wo, qb, kb, vt, ctq, ctk, 3072, 3072);
    } else {
      k_gemm_f32<0><<<dim3(24,8),256,0,stream>>>(hx, sqW+wo, nullptr, qb, nullptr,nullptr,nullptr, 3072,1024,1024);
      k_gemm_f32<0><<<dim3(24,8),256,0,stream>>>(hx, skW+wo, nullptr, kb, nullptr,nullptr,nullptr, 3072,1024,1024);
      k_gemm_f32<3><<<dim3(24,8),256,0,stream>>>(hx, svW+wo, nullptr, vt, nullptr,nullptr,nullptr, 3072,1024,1024);
      k_rope<<<6144,256,0,stream>>>(qb, kb, rope);
    }
    k_flash<<<dim3(48,16),256,0,stream>>>(qb, kb, vt, ob, 3072);
    if (splitok){
      k_gemm_part<<<dim3(24,8,4),256,0,stream>>>(ob, soWb+wo, pp, 3072,1024,1024,256);
      k_reduce_ln<0><<<3072,256,0,stream>>>(pp, 4, sob+(size_t)i*1024,
          (i==0 ? x_in : (const float*)x), x, mi+2048, nullptr, nullptr, hx);
    } else if (pre){
      k_gemm_bf16<2><<<dim3(24,8),256,0,stream>>>(ob, soWb+wo, sob+(size_t)i*1024, nullptr, x, x, mi+2048, 3072,1024,1024);
      k_ln_mod<<<3072,256,0,stream>>>(x, nullptr, nullptr, hx);
    } else {
      k_gemm_f32<2><<<dim3(24,8),256,0,stream>>>(ob, soW+wo, sob+(size_t)i*1024, nullptr, x, x, mi+2048, 3072,1024,1024);
      k_ln_mod<<<3072,256,0,stream>>>(x, nullptr, nullptr, hx);
    }
    // --- cross attention ---
    if (splitok){
      k_gemm_part<<<dim3(24,8,4),256,0,stream>>>(hx, cqWb+wo, pp, 3072,1024,1024,256);
      k_reduce<4><<<3072,256,0,stream>>>(pp, 4, nullptr, nullptr, nullptr, nullptr, qb, MN, 1024);
      k_kv64<<<dim3(8,32),256,0,stream>>>(ctxb, ckWb+wo, cvWb+wo, kb, vt, 512);
    } else if (pre){
      k_gemm_bf16<4><<<dim3(24,8),256,0,stream>>>(hx, cqWb+wo, nullptr, qb, nullptr,nullptr,nullptr, 3072,1024,1024);
      k_kv64<<<dim3(8,32),256,0,stream>>>(ctxb, ckWb+wo, cvWb+wo, kb, vt, 512);
    } else {
      k_gemm_f32<4><<<dim3(24,8),256,0,stream>>>(hx, cqW+wo, nullptr, qb, nullptr,nullptr,nullptr, 3072,1024,1024);
      k_gemm_f32<0><<<dim3(4,8),256,0,stream>>>(ctxb, ckW+wo, nullptr, kb, nullptr,nullptr,nullptr, 512,1024,1024);
      k_gemm_f32<3><<<dim3(4,8),256,0,stream>>>(ctxb, cvW+wo, nullptr, vt, nullptr,nullptr,nullptr, 512,1024,1024);
    }
    k_flash<<<dim3(48,16),256,0,stream>>>(qb, kb, vt, ob, 512);
    if (splitok){
      k_gemm_part<<<dim3(24,8,4),256,0,stream>>>(ob, coWb+wo, pp, 3072,1024,1024,256);
      k_reduce_ln<1><<<3072,256,0,stream>>>(pp, 4, cob+(size_t)i*1024, x, x, nullptr, mi+3072, mi+4096, hx);
    } else if (pre){
      k_gemm_bf16<2><<<dim3(24,8),256,0,stream>>>(ob, coWb+wo, cob+(size_t)i*1024, nullptr, x, x, nullptr, 3072,1024,1024);
      k_ln_mod<<<3072,256,0,stream>>>(x, mi+3072, mi+4096, hx);
    } else {
      k_gemm_f32<2><<<dim3(24,8),256,0,stream>>>(ob, coW+wo, cob+(size_t)i*1024, nullptr, x, x, nullptr, 3072,1024,1024);
      k_ln_mod<<<3072,256,0,stream>>>(x, mi+3072, mi+4096, hx);
    }
    // --- MLP ---
    if (pre){
      k_gemm_bf16<1><<<dim3(24,32),256,0,stream>>>(hx, f1Wb+wof, f1b+(size_t)i*4096, mid, nullptr,nullptr,nullptr, 3072,4096,1024);
    } else {
      k_gemm_f32<1><<<dim3(24,32),256,0,stream>>>(hx, f1W+wof, f1b+(size_t)i*4096, mid, nullptr,nullptr,nullptr, 3072,4096,1024);
    }
    if (splitok){
      k_gemm_part<<<dim3(24,8,4),256,0,stream>>>(mid, f2Wb+wof, pp, 3072,1024,4096,1024);
      if (i == 0)
        k_reduce_ln<1><<<3072,256,0,stream>>>(pp, 4, f2b, x, x, mi+5120, mi2+0, mi2+1024, hx);
      else
        k_reduce<2><<<3072,256,0,stream>>>(pp, 4, f2b+1024, x, x, mi+5120, nullptr, MN, 1024);
    } else if (pre){
      k_gemm_bf16<2><<<dim3(24,8),256,0,stream>>>(mid, f2Wb+wof, f2b+(size_t)i*1024, nullptr, x, x, mi+5120, 3072,1024,4096);
    } else {
      k_gemm_f32<2><<<dim3(24,8),256,0,stream>>>(mid, f2W+wof, f2b+(size_t)i*1024, nullptr, x, x, mi+5120, 3072,1024,4096);
    }
  }
}

// Round 10
// 763.656 us; speedup vs baseline: 1.2382x; 1.2382x over previous
//
#include <hip/hip_runtime.h>
#include <math.h>

typedef __attribute__((ext_vector_type(8))) short bf16x8;
typedef __attribute__((ext_vector_type(4))) float f32x4;
typedef unsigned short u16;
typedef unsigned int u32;

#define DEV static __device__ __forceinline__

typedef __attribute__((address_space(3))) u32 lds_u32;
typedef const __attribute__((address_space(1))) u32 glb_u32;

DEV void gload16(const void* g, void* l){
  __builtin_amdgcn_global_load_lds((glb_u32*)g, (lds_u32*)l, 16, 0, 0);
}

DEV u16 f2bf(float f){
  u32 u = __builtin_bit_cast(u32, f);
  u32 r = (u + 0x7fffu + ((u >> 16) & 1u)) >> 16;
  return (u16)r;
}
DEV float bf2f(u16 h){
  u32 u = ((u32)h) << 16;
  return __builtin_bit_cast(float, u);
}
DEV u32 cvtpk(float a, float b){
  u32 r;
  asm("v_cvt_pk_bf16_f32 %0, %1, %2" : "=v"(r) : "v"(a), "v"(b));
  return r;
}
DEV float gelu_exact(float x){ return 0.5f*x*(1.f+erff(x*0.70710678118654752f)); }

#define QSCALE 0.18033688f   /* 0.125 * log2(e) */

DEV void xcd_remap(int &bx, int &by){
  int gx = gridDim.x, gy = gridDim.y;
  int n = gx*gy;
  if ((n & 7) == 0){
    int id = by*gx + bx;
    int q = n >> 3;
    int sid = (id & 7)*q + (id >> 3);
    bx = sid % gx;
    by = sid / gx;
  }
}

// ---------------- elementwise ----------------
__global__ __launch_bounds__(256) void k_copy_f32(const float* __restrict__ in, float* __restrict__ out, int n4){
  int i = blockIdx.x*256 + threadIdx.x;
  if (i < n4) ((float4*)out)[i] = ((const float4*)in)[i];
}

__global__ __launch_bounds__(256) void k_cvt_bf16(const float* __restrict__ in, u16* __restrict__ out, int n4){
  int i = blockIdx.x*256 + threadIdx.x;
  if (i < n4){
    float4 v = ((const float4*)in)[i];
    ushort4 o;
    o.x = f2bf(v.x); o.y = f2bf(v.y); o.z = f2bf(v.z); o.w = f2bf(v.w);
    ((ushort4*)out)[i] = o;
  }
}

struct CvtArgs { const float4* s[16]; ushort4* d[16]; };
__global__ __launch_bounds__(256) void k_cvt_all(CvtArgs a){
  int i = blockIdx.x*256 + threadIdx.x;
  int seg = i >> 19;
  int off = i & 0x7FFFF;
  float4 v = a.s[seg][off];
  ushort4 o;
  o.x = f2bf(v.x); o.y = f2bf(v.y); o.z = f2bf(v.z); o.w = f2bf(v.w);
  a.d[seg][off] = o;
}

__global__ __launch_bounds__(256) void k_trig(const float* __restrict__ rope,
    float2* __restrict__ ctq, float2* __restrict__ ctk){
  int i = blockIdx.x*256 + threadIdx.x;
  int d = i & 63;
  float a = rope[i];
  float c = cosf(a), s = sinf(a);
  float sg = (d < 32) ? -s : s;
  ctk[i] = make_float2(c, sg);
  ctq[i] = make_float2(c*QSCALE, sg*QSCALE);
}

__global__ __launch_bounds__(256) void k_ada(const float* __restrict__ te,
    const float* __restrict__ adaW, const float* __restrict__ adab,
    float* __restrict__ mods){
  int row = blockIdx.x*4 + (threadIdx.x>>6);
  int lane = threadIdx.x & 63;
  const float* wr = adaW + (size_t)row*1024;
  float s = 0.f;
  #pragma unroll
  for (int j=0; j<4; j++){
    int c = lane*4 + j*256;
    float4 a = *(const float4*)(te + c);
    float4 b = *(const float4*)(wr + c);
    s += a.x*b.x + a.y*b.y + a.z*b.z + a.w*b.w;
  }
  #pragma unroll
  for (int off=32; off; off>>=1) s += __shfl_down(s, off);
  if (!lane) mods[row] = s + adab[row];
}

__global__ __launch_bounds__(256) void k_ln_mod(const float* __restrict__ x,
    const float* __restrict__ sh, const float* __restrict__ sc,
    u16* __restrict__ out){
  int row = blockIdx.x, t = threadIdx.x;
  const float* xr = x + (size_t)row*1024;
  float4 v = ((const float4*)xr)[t];
  float s  = v.x+v.y+v.z+v.w;
  float sq = v.x*v.x+v.y*v.y+v.z*v.z+v.w*v.w;
  #pragma unroll
  for (int off=32; off; off>>=1){ s += __shfl_down(s,off); sq += __shfl_down(sq,off); }
  __shared__ float red[8];
  int w = t>>6, lane = t&63;
  if (!lane){ red[w] = s; red[4+w] = sq; }
  __syncthreads();
  s  = red[0]+red[1]+red[2]+red[3];
  sq = red[4]+red[5]+red[6]+red[7];
  float mean = s*(1.f/1024.f);
  float var  = sq*(1.f/1024.f) - mean*mean;
  float rst  = rsqrtf(var + 1e-6f);
  float vv[4] = {v.x, v.y, v.z, v.w};
  ushort4 o;
  u16 ob[4];
  #pragma unroll
  for (int j=0;j<4;j++){
    int col = t*4+j;
    float y = (vv[j]-mean)*rst;
    if (sh) y = y*(1.f + sc[col]) + sh[col];
    ob[j] = f2bf(y);
  }
  o.x=ob[0]; o.y=ob[1]; o.z=ob[2]; o.w=ob[3];
  *(ushort4*)(out + (size_t)row*1024 + t*4) = o;
}

// RoPE in-place (fallback path only)
__global__ __launch_bounds__(256) void k_rope(u16* __restrict__ q, u16* __restrict__ k,
    const float* __restrict__ rope){
  int idx = blockIdx.x*256 + threadIdx.x;
  int d = idx & 31;
  int h = (idx >> 5) & 15;
  int p = idx >> 9;
  const float* rr = rope + (size_t)p*64;
  float a0 = rr[d], a1 = rr[d+32];
  float c0 = cosf(a0), s0 = sinf(a0);
  float c1 = cosf(a1), s1 = sinf(a1);
  size_t o = (size_t)p*1024 + h*64 + d;
  float q0 = bf2f(q[o]), q1 = bf2f(q[o+32]);
  q[o]    = f2bf((q0*c0 - q1*s0)*QSCALE);
  q[o+32] = f2bf((q1*c1 + q0*s1)*QSCALE);
  float k0 = bf2f(k[o]), k1 = bf2f(k[o+32]);
  k[o]    = f2bf(k0*c0 - k1*s0);
  k[o+32] = f2bf(k1*c1 + k0*s1);
}

// ---------------- shared GEMM mainloop (bf16 W, dbuf + prefetch) ----------------
DEV void gemm_loop(const u16* __restrict__ X, const u16* __restrict__ W,
                   int bm, int bn, int ld, int lenK, u16* As, u16* Bs, f32x4 acc[4][4])
{
  int t = threadIdx.x;
  int w = t>>6, lane = t&63;
  int wr = (w>>1)*64, wc = (w&1)*64;
  int fr = lane&15, g = lane>>4;
  int arow = lane>>2, acol = (lane&3)*8;
  const u16* xp = X + (size_t)(bm + w*32 + arow)*ld + acol;
  const u16* wp = W + (size_t)(bn + w*32 + arow)*ld + acol;
  int nk = lenK >> 5;
  {
    u16* a = As + w*1024; u16* b = Bs + w*1024;
    gload16(xp, a);             gload16(xp + (size_t)16*ld, a + 512);
    gload16(wp, b);             gload16(wp + (size_t)16*ld, b + 512);
  }
  for (int kt = 0; kt < nk; ++kt){
    __syncthreads();
    int cur = kt & 1;
    if (kt + 1 < nk){
      int nb = cur ^ 1;
      int k0 = (kt+1) << 5;
      u16* a = As + nb*4096 + w*1024; u16* b = Bs + nb*4096 + w*1024;
      gload16(xp + k0, a);        gload16(xp + k0 + (size_t)16*ld, a + 512);
      gload16(wp + k0, b);        gload16(wp + k0 + (size_t)16*ld, b + 512);
    }
    const u16* ab = As + cur*4096;
    const u16* bb = Bs + cur*4096;
    bf16x8 a[4], b[4];
    #pragma unroll
    for (int i=0;i<4;i++) a[i] = *(const bf16x8*)(ab + (wr+i*16+fr)*32 + g*8);
    #pragma unroll
    for (int i=0;i<4;i++) b[i] = *(const bf16x8*)(bb + (wc+i*16+fr)*32 + g*8);
    __builtin_amdgcn_s_setprio(1);
    #pragma unroll
    for (int i=0;i<4;i++)
      #pragma unroll
      for (int j=0;j<4;j++)
        acc[i][j] = __builtin_amdgcn_mfma_f32_16x16x32_bf16(a[i], b[j], acc[i][j], 0, 0, 0);
    __builtin_amdgcn_s_setprio(0);
  }
}

// ---------------- standalone GEMM (bf16 W): EPI 1 gelu, 2 gated-residual, 4 scaled ----------------
template<int EPI>
__global__ __launch_bounds__(256) void k_gemm_bf16(
    const u16* __restrict__ X, const u16* __restrict__ W,
    const float* __restrict__ bias,
    u16* __restrict__ Yout,
    const float* __restrict__ resin, float* __restrict__ resout,
    const float* __restrict__ gate,
    int M, int N, int K)
{
  __shared__ __align__(16) u16 As[2*128*32];
  __shared__ __align__(16) u16 Bs[2*128*32];
  int bx = blockIdx.x, by = blockIdx.y;
  xcd_remap(bx, by);
  int bm = bx*128, bn = by*128;
  f32x4 acc[4][4] = {};
  gemm_loop(X, W, bm, bn, K, K, As, Bs, acc);
  int lane = threadIdx.x & 63, w = threadIdx.x>>6;
  int wr = (w>>1)*64, wc = (w&1)*64;
  int fr = lane&15, g = lane>>4;
  #pragma unroll
  for (int i=0;i<4;i++){
    #pragma unroll
    for (int j=0;j<4;j++){
      int col = bn + wc + j*16 + fr;
      float bv = bias ? bias[col] : 0.f;
      #pragma unroll
      for (int r=0;r<4;r++){
        int row = bm + wr + i*16 + g*4 + r;
        float y = acc[i][j][r] + bv;
        if (EPI == 1){
          Yout[(size_t)row*N + col] = f2bf(gelu_exact(y));
        } else if (EPI == 2){
          float gt = gate ? gate[col] : 1.f;
          resout[(size_t)row*N + col] = resin[(size_t)row*N + col] + gt*y;
        } else {
          Yout[(size_t)row*N + col] = f2bf(y*QSCALE);
        }
      }
    }
  }
}

// ---------------- split-K partial GEMM ----------------
__global__ __launch_bounds__(256) void k_gemm_part(
    const u16* __restrict__ X, const u16* __restrict__ W,
    float* __restrict__ pp, int M, int N, int K, int Ks)
{
  __shared__ __align__(16) u16 As[2*128*32];
  __shared__ __align__(16) u16 Bs[2*128*32];
  int bx = blockIdx.x, by = blockIdx.y;
  xcd_remap(bx, by);
  int s = blockIdx.z;
  int bm = bx*128, bn = by*128;
  f32x4 acc[4][4] = {};
  gemm_loop(X + (size_t)s*Ks, W + (size_t)s*Ks, bm, bn, K, Ks, As, Bs, acc);
  float* out = pp + (size_t)s*M*N;
  int lane = threadIdx.x & 63, w = threadIdx.x>>6;
  int wr = (w>>1)*64, wc = (w&1)*64;
  int fr = lane&15, g = lane>>4;
  #pragma unroll
  for (int i=0;i<4;i++)
    #pragma unroll
    for (int j=0;j<4;j++){
      int col = bn + wc + j*16 + fr;
      #pragma unroll
      for (int r=0;r<4;r++){
        int row = bm + wr + i*16 + g*4 + r;
        out[(size_t)row*N + col] = acc[i][j][r];
      }
    }
}

// ---------------- split-K reduce ----------------
template<int EPI>
__global__ __launch_bounds__(256) void k_reduce(
    const float* __restrict__ pp, int S, const float* __restrict__ bias,
    const float* __restrict__ resin, float* __restrict__ resout,
    const float* __restrict__ gate, u16* __restrict__ Ybf,
    int MN, int N)
{
  int idx = blockIdx.x*256 + threadIdx.x;
  int base = idx*4;
  if (base >= MN) return;
  float4 s4 = *(const float4*)(pp + base);
  for (int s=1; s<S; ++s){
    float4 t4 = *(const float4*)(pp + (size_t)s*MN + base);
    s4.x += t4.x; s4.y += t4.y; s4.z += t4.z; s4.w += t4.w;
  }
  int col = base & (N-1);
  float b0=0,b1=0,b2=0,b3=0;
  if (bias){ b0=bias[col]; b1=bias[col+1]; b2=bias[col+2]; b3=bias[col+3]; }
  if (EPI == 2){
    float g0=1,g1=1,g2=1,g3=1;
    if (gate){ g0=gate[col]; g1=gate[col+1]; g2=gate[col+2]; g3=gate[col+3]; }
    float4 rv = *(const float4*)(resin + base);
    float4 o;
    o.x = rv.x + g0*(s4.x+b0);
    o.y = rv.y + g1*(s4.y+b1);
    o.z = rv.z + g2*(s4.z+b2);
    o.w = rv.w + g3*(s4.w+b3);
    *(float4*)(resout + base) = o;
  } else {
    ushort4 o;
    o.x = f2bf((s4.x+b0)*QSCALE);
    o.y = f2bf((s4.y+b1)*QSCALE);
    o.z = f2bf((s4.z+b2)*QSCALE);
    o.w = f2bf((s4.w+b3)*QSCALE);
    *(ushort4*)(Ybf + base) = o;
  }
}

// ---------------- fused split-K reduce + residual + LayerNorm ----------------
template<int MOD>
__global__ __launch_bounds__(256) void k_reduce_ln(
    const float* __restrict__ pp, int S, const float* __restrict__ bias,
    const float* __restrict__ resin, float* __restrict__ resout,
    const float* __restrict__ gate,
    const float* __restrict__ sh, const float* __restrict__ sc,
    u16* __restrict__ hx)
{
  int row = blockIdx.x, t = threadIdx.x;
  size_t base = (size_t)row*1024 + t*4;
  const size_t MN = (size_t)3072*1024;
  float4 s4 = *(const float4*)(pp + base);
  for (int s=1; s<S; ++s){
    float4 t4 = *(const float4*)(pp + (size_t)s*MN + base);
    s4.x += t4.x; s4.y += t4.y; s4.z += t4.z; s4.w += t4.w;
  }
  int col = t*4;
  float b0=0,b1=0,b2=0,b3=0;
  if (bias){ b0=bias[col]; b1=bias[col+1]; b2=bias[col+2]; b3=bias[col+3]; }
  float g0=1,g1=1,g2=1,g3=1;
  if (gate){ g0=gate[col]; g1=gate[col+1]; g2=gate[col+2]; g3=gate[col+3]; }
  float4 rv = *(const float4*)(resin + base);
  float y[4];
  y[0] = rv.x + g0*(s4.x+b0);
  y[1] = rv.y + g1*(s4.y+b1);
  y[2] = rv.z + g2*(s4.z+b2);
  y[3] = rv.w + g3*(s4.w+b3);
  float4 ov; ov.x=y[0]; ov.y=y[1]; ov.z=y[2]; ov.w=y[3];
  *(float4*)(resout + base) = ov;
  float s  = y[0]+y[1]+y[2]+y[3];
  float sq = y[0]*y[0]+y[1]*y[1]+y[2]*y[2]+y[3]*y[3];
  #pragma unroll
  for (int off=32; off; off>>=1){ s += __shfl_down(s,off); sq += __shfl_down(sq,off); }
  __shared__ float red[8];
  int w = t>>6, lane = t&63;
  if (!lane){ red[w] = s; red[4+w] = sq; }
  __syncthreads();
  s  = red[0]+red[1]+red[2]+red[3];
  sq = red[4]+red[5]+red[6]+red[7];
  float mean = s*(1.f/1024.f);
  float var  = sq*(1.f/1024.f) - mean*mean;
  float rst  = rsqrtf(var + 1e-6f);
  ushort4 o;
  u16 ob[4];
  #pragma unroll
  for (int j=0;j<4;j++){
    float yy = (y[j]-mean)*rst;
    if (MOD) yy = yy*(1.f + sc[col+j]) + sh[col+j];
    ob[j] = f2bf(yy);
  }
  o.x=ob[0]; o.y=ob[1]; o.z=ob[2]; o.w=ob[3];
  *(ushort4*)(hx + base) = o;
}

// ---------------- fused QKV GEMM (+ fused rope on q,k) ----------------
template<int MODE>
__global__ __launch_bounds__(256) void k_qkv(
    const u16* __restrict__ X,
    const u16* __restrict__ W0, const u16* __restrict__ W1, const u16* __restrict__ W2,
    u16* __restrict__ Y0, u16* __restrict__ Y1, u16* __restrict__ VT,
    const float2* __restrict__ ctq, const float2* __restrict__ ctk,
    int M, int ldvt)
{
  __shared__ __align__(16) u16 As[2*128*32];
  __shared__ __align__(16) u16 Bs[2*128*32];
  int bx = blockIdx.x, by = blockIdx.y;
  xcd_remap(bx, by);
  int bm = bx*128, bn = by*128;
  int sel = bn >> 10;
  int bnl = bn & 1023;
  const u16* W = (sel==0 ? W0 : (sel==1 ? W1 : W2));
  f32x4 acc[4][4] = {};
  gemm_loop(X, W, bm, bnl, 1024, 1024, As, Bs, acc);
  int lane = threadIdx.x & 63, w = threadIdx.x>>6;
  int wr = (w>>1)*64, wc = (w&1)*64;
  int fr = lane&15, g = lane>>4;
  if (sel < 2){
    u16* Y = (sel==0) ? Y0 : Y1;
    const float2* ct = (sel==0) ? ctq : ctk;
    #pragma unroll
    for (int i=0;i<4;i++)
      #pragma unroll
      for (int j=0;j<4;j++){
        int col = bnl + wc + j*16 + fr;
        int d = j*16 + fr;
        #pragma unroll
        for (int r=0;r<4;r++){
          int row = bm + wr + i*16 + g*4 + r;
          float2 cs = ct[row*64 + d];
          float yv = acc[i][j][r]*cs.x + acc[i][j^2][r]*cs.y;
          Y[(size_t)row*1024 + col] = f2bf(yv);
        }
      }
  } else {
    #pragma unroll
    for (int i=0;i<4;i++)
      #pragma unroll
      for (int j=0;j<4;j++){
        int col = bnl + wc + j*16 + fr;
        int row0 = bm + wr + i*16 + g*4;
        uint2 pk;
        pk.x = cvtpk(acc[i][j][0], acc[i][j][1]);
        pk.y = cvtpk(acc[i][j][2], acc[i][j][3]);
        *(uint2*)(VT + (size_t)col*ldvt + row0) = pk;
      }
  }
}

// ---------------- cross K/V GEMM: 64x64 tiles, grid (8,32)=256 balanced ----------------
__global__ __launch_bounds__(256) void k_kv64(
    const u16* __restrict__ X,
    const u16* __restrict__ Wk, const u16* __restrict__ Wv,
    u16* __restrict__ Kout, u16* __restrict__ VTout, int ldvt)
{
  __shared__ __align__(16) u16 As[2*64*32];
  __shared__ __align__(16) u16 Bs[2*64*32];
  int bx = blockIdx.x, by = blockIdx.y;
  xcd_remap(bx, by);
  int bm = bx*64;
  int sel = by >> 4;
  int bnl = (by & 15)*64;
  const u16* W = sel ? Wv : Wk;
  int t = threadIdx.x, w = t>>6, lane = t&63;
  int wr = (w>>1)*32, wc = (w&1)*32;
  int fr = lane&15, g = lane>>4;
  f32x4 acc[2][2] = {};
  int arow = lane>>2, acol = (lane&3)*8;
  const u16* xp = X + (size_t)(bm + w*16 + arow)*1024 + acol;
  const u16* wp = W + (size_t)(bnl + w*16 + arow)*1024 + acol;
  {
    gload16(xp, As + w*512);
    gload16(wp, Bs + w*512);
  }
  for (int kt = 0; kt < 32; ++kt){
    __syncthreads();
    int cur = kt & 1;
    if (kt + 1 < 32){
      int nb = cur ^ 1;
      int k0 = (kt+1) << 5;
      gload16(xp + k0, As + nb*2048 + w*512);
      gload16(wp + k0, Bs + nb*2048 + w*512);
    }
    const u16* ab = As + cur*2048;
    const u16* bb = Bs + cur*2048;
    bf16x8 a[2], b[2];
    #pragma unroll
    for (int i=0;i<2;i++) a[i] = *(const bf16x8*)(ab + (wr+i*16+fr)*32 + g*8);
    #pragma unroll
    for (int i=0;i<2;i++) b[i] = *(const bf16x8*)(bb + (wc+i*16+fr)*32 + g*8);
    __builtin_amdgcn_s_setprio(1);
    #pragma unroll
    for (int i=0;i<2;i++)
      #pragma unroll
      for (int j=0;j<2;j++)
        acc[i][j] = __builtin_amdgcn_mfma_f32_16x16x32_bf16(a[i], b[j], acc[i][j], 0, 0, 0);
    __builtin_amdgcn_s_setprio(0);
  }
  #pragma unroll
  for (int i=0;i<2;i++)
    #pragma unroll
    for (int j=0;j<2;j++){
      int col = bnl + wc + j*16 + fr;
      if (sel == 0){
        #pragma unroll
        for (int r=0;r<4;r++){
          int row = bm + wr + i*16 + g*4 + r;
          Kout[(size_t)row*1024 + col] = f2bf(acc[i][j][r]);
        }
      } else {
        int row0 = bm + wr + i*16 + g*4;
        uint2 pk;
        pk.x = cvtpk(acc[i][j][0], acc[i][j][1]);
        pk.y = cvtpk(acc[i][j][2], acc[i][j][3]);
        *(uint2*)(VTout + (size_t)col*ldvt + row0) = pk;
      }
    }
}

// ---------------- fallback GEMM (f32 weights in-flight) ----------------
template<int EPI>
__global__ __launch_bounds__(256) void k_gemm_f32(
    const u16* __restrict__ X, const float* __restrict__ W,
    const float* __restrict__ bias,
    u16* __restrict__ Yout,
    const float* __restrict__ resin, float* __restrict__ resout,
    const float* __restrict__ gate,
    int M, int N, int K)
{
  __shared__ __align__(16) u16 As[128][32];
  __shared__ __align__(16) u16 Bs[128][40];
  int bx = blockIdx.x, by = blockIdx.y;
  xcd_remap(bx, by);
  int bm = bx*128, bn = by*128;
  int t = threadIdx.x;
  int w = t>>6, lane = t&63;
  int wr = (w>>1)*64, wc = (w&1)*64;
  int fr = lane&15, g = lane>>4;
  f32x4 acc[4][4] = {};
  int arow = lane>>2, acol = (lane&3)*8;
  int srow = t>>2, scol = (t&3)*8;
  for (int k0=0; k0<K; k0+=32){
    #pragma unroll
    for (int inst=0; inst<2; ++inst){
      int r = w*32 + inst*16 + arow;
      gload16(X + (size_t)(bm+r)*K + k0 + acol, &As[w*32+inst*16][0]);
    }
    #pragma unroll
    for (int it=0; it<2; ++it){
      const float* wp = W + (size_t)(bn+srow+it*64)*K + k0 + scol;
      float4 f0 = *(const float4*)(wp);
      float4 f1 = *(const float4*)(wp+4);
      uint4 bw;
      bw.x = (u32)f2bf(f0.x) | ((u32)f2bf(f0.y)<<16);
      bw.y = (u32)f2bf(f0.z) | ((u32)f2bf(f0.w)<<16);
      bw.z = (u32)f2bf(f1.x) | ((u32)f2bf(f1.y)<<16);
      bw.w = (u32)f2bf(f1.z) | ((u32)f2bf(f1.w)<<16);
      *(uint4*)&Bs[srow+it*64][scol] = bw;
    }
    __syncthreads();
    bf16x8 a[4], b[4];
    #pragma unroll
    for (int i=0;i<4;i++) a[i] = *(const bf16x8*)&As[wr+i*16+fr][g*8];
    #pragma unroll
    for (int i=0;i<4;i++) b[i] = *(const bf16x8*)&Bs[wc+i*16+fr][g*8];
    #pragma unroll
    for (int i=0;i<4;i++)
      #pragma unroll
      for (int j=0;j<4;j++)
        acc[i][j] = __builtin_amdgcn_mfma_f32_16x16x32_bf16(a[i], b[j], acc[i][j], 0, 0, 0);
    __syncthreads();
  }
  #pragma unroll
  for (int i=0;i<4;i++){
    #pragma unroll
    for (int j=0;j<4;j++){
      int col = bn + wc + j*16 + fr;
      float bv = bias ? bias[col] : 0.f;
      #pragma unroll
      for (int r=0;r<4;r++){
        int row = bm + wr + i*16 + g*4 + r;
        float y = acc[i][j][r] + bv;
        if (EPI == 0){
          Yout[(size_t)row*N + col] = f2bf(y);
        } else if (EPI == 1){
          Yout[(size_t)row*N + col] = f2bf(gelu_exact(y));
        } else if (EPI == 2){
          float gt = gate ? gate[col] : 1.f;
          resout[(size_t)row*N + col] = resin[(size_t)row*N + col] + gt*y;
        } else if (EPI == 3){
          Yout[(size_t)col*M + row] = f2bf(y);
        } else {
          Yout[(size_t)row*N + col] = f2bf(y*QSCALE);
        }
      }
    }
  }
}

// ---------------- Flash attention (R6 structure; Ps pad 64 + XOR swizzle => 40KB LDS, 4 blocks/CU) ----------------
__global__ __launch_bounds__(256) void k_flash(
    const u16* __restrict__ Q, const u16* __restrict__ Kb, const u16* __restrict__ VT,
    u16* __restrict__ O, int Lkv)
{
  __shared__ __align__(16) u16 Ks[2*64*64];
  __shared__ __align__(16) u16 Vs[2*64*64];
  __shared__ __align__(16) u16 Ps[4*16*64];
  int bx = blockIdx.x, by = blockIdx.y;
  xcd_remap(bx, by);
  int h = by;
  int q0 = bx*64;
  int t = threadIdx.x, w = t>>6, lane = t&63;
  int fr = lane&15, g = lane>>4;
  const u16* qrow = Q + (size_t)(q0 + w*16 + fr)*1024 + h*64;
  bf16x8 aq0 = *(const bf16x8*)(qrow + g*8);
  bf16x8 aq1 = *(const bf16x8*)(qrow + 32 + g*8);
  f32x4 accO[4] = {};
  float l = 0.f;
  int slot = lane & 7, rop = lane >> 3;
  const u16* kbase = Kb + (size_t)h*64;
  const u16* vbase = VT + (size_t)h*64*Lkv;
  int nt = Lkv >> 6;
  u16* pbase = Ps + w*1024 + fr*64;          // per-(wave,q) P row
  int pswz = (fr & 7) << 3;                  // u16-offset XOR swizzle
  {
    #pragma unroll
    for (int inst=0; inst<2; ++inst){
      int row = w*16 + inst*8 + rop;
      int ss = slot ^ (row & 7);
      gload16(kbase + (size_t)row*1024 + ss*8, Ks + (w*16+inst*8)*64);
      gload16(vbase + (size_t)row*Lkv + ss*8, Vs + (w*16+inst*8)*64);
    }
  }
  for (int tt=0; tt<nt; ++tt){
    __syncthreads();
    int cur = tt & 1;
    if (tt+1 < nt){
      int nb = cur ^ 1;
      int k0 = (tt+1) << 6;
      #pragma unroll
      for (int inst=0; inst<2; ++inst){
        int row = w*16 + inst*8 + rop;
        int ss = slot ^ (row & 7);
        gload16(kbase + (size_t)(k0+row)*1024 + ss*8, Ks + nb*4096 + (w*16+inst*8)*64);
        gload16(vbase + (size_t)row*Lkv + k0 + ss*8, Vs + nb*4096 + (w*16+inst*8)*64);
      }
    }
    const u16* kc = Ks + cur*4096;
    const u16* vc = Vs + cur*4096;
    f32x4 st[4] = {};
    __builtin_amdgcn_s_setprio(1);
    #pragma unroll
    for (int kb=0;kb<4;kb++){
      int rowK = kb*16 + fr;
      bf16x8 b0 = *(const bf16x8*)(kc + rowK*64 + ((g  ) ^ (rowK&7))*8);
      bf16x8 b1 = *(const bf16x8*)(kc + rowK*64 + ((4+g) ^ (rowK&7))*8);
      st[kb] = __builtin_amdgcn_mfma_f32_16x16x32_bf16(b0, aq0, st[kb], 0,0,0);
      st[kb] = __builtin_amdgcn_mfma_f32_16x16x32_bf16(b1, aq1, st[kb], 0,0,0);
    }
    __builtin_amdgcn_s_setprio(0);
    float ts = 0.f;
    u32 pk[8];
    #pragma unroll
    for (int kb=0;kb<4;kb++){
      float p0 = exp2f(st[kb][0]);
      float p1 = exp2f(st[kb][1]);
      float p2 = exp2f(st[kb][2]);
      float p3 = exp2f(st[kb][3]);
      ts += (p0+p1)+(p2+p3);
      pk[kb*2]   = cvtpk(p0,p1);
      pk[kb*2+1] = cvtpk(p2,p3);
    }
    ts += __shfl_xor(ts, 16);
    ts += __shfl_xor(ts, 32);
    l += ts;
    #pragma unroll
    for (int kb=0;kb<4;kb++){
      uint2 pv; pv.x = pk[kb*2]; pv.y = pk[kb*2+1];
      *(uint2*)(pbase + ((kb*16 + g*4) ^ pswz)) = pv;
    }
    bf16x8 ap0 = *(const bf16x8*)(pbase + ((g*8) ^ pswz));
    bf16x8 ap1 = *(const bf16x8*)(pbase + ((32 + g*8) ^ pswz));
    __builtin_amdgcn_s_setprio(1);
    #pragma unroll
    for (int nd=0; nd<4; nd++){
      int rowV = nd*16 + fr;
      bf16x8 b0 = *(const bf16x8*)(vc + rowV*64 + ((g  ) ^ (rowV&7))*8);
      bf16x8 b1 = *(const bf16x8*)(vc + rowV*64 + ((4+g) ^ (rowV&7))*8);
      accO[nd] = __builtin_amdgcn_mfma_f32_16x16x32_bf16(ap0, b0, accO[nd], 0,0,0);
      accO[nd] = __builtin_amdgcn_mfma_f32_16x16x32_bf16(ap1, b1, accO[nd], 0,0,0);
    }
    __builtin_amdgcn_s_setprio(0);
  }
  float rl = 1.f / l;
  #pragma unroll
  for (int r=0;r<4;r++){
    float rlq = __shfl(rl, g*4+r);
    int row = q0 + w*16 + g*4 + r;
    #pragma unroll
    for (int nd=0; nd<4; nd++)
      O[(size_t)row*1024 + h*64 + nd*16 + fr] = f2bf(accO[nd][r] * rlq);
  }
}

// ---------------- launch ----------------
extern "C" void kernel_launch(void* const* d_in, const int* in_sizes, int n_in,
                              void* d_out, int out_size, void* d_ws, size_t ws_size,
                              hipStream_t stream){
  const float* x_in = (const float*)d_in[0];
  const float* te   = (const float*)d_in[1];
  const float* ctx  = (const float*)d_in[2];
  const float* rope = (const float*)d_in[3];
  const float* adaW = (const float*)d_in[4];
  const float* adab = (const float*)d_in[5];
  const float* sqW  = (const float*)d_in[6];
  const float* skW  = (const float*)d_in[7];
  const float* svW  = (const float*)d_in[8];
  const float* soW  = (const float*)d_in[9];
  const float* sob  = (const float*)d_in[10];
  const float* cqW  = (const float*)d_in[11];
  const float* ckW  = (const float*)d_in[12];
  const float* cvW  = (const float*)d_in[13];
  const float* coW  = (const float*)d_in[14];
  const float* cob  = (const float*)d_in[15];
  const float* f1W  = (const float*)d_in[16];
  const float* f1b  = (const float*)d_in[17];
  const float* f2W  = (const float*)d_in[18];
  const float* f2b  = (const float*)d_in[19];
  float* x = (float*)d_out;

  char* p = (char*)d_ws;
  size_t used = 0;
  auto alloc = [&](size_t bytes){
    void* r = (void*)(p + used);
    used += (bytes + 255) & ~(size_t)255;
    return r;
  };
  u16* hx   = (u16*)alloc((size_t)3072*1024*2);
  u16* qb   = (u16*)alloc((size_t)3072*1024*2);
  u16* kb   = (u16*)alloc((size_t)3072*1024*2);
  u16* vt   = (u16*)alloc((size_t)1024*3072*2);
  u16* ob   = (u16*)alloc((size_t)3072*1024*2);
  u16* mid  = (u16*)alloc((size_t)3072*4096*2);
  u16* ctxb = (u16*)alloc((size_t)512*1024*2);
  float* mods = (float*)alloc((size_t)2*6144*4);
  float2* ctq = (float2*)alloc((size_t)3072*64*8);
  float2* ctk = (float2*)alloc((size_t)3072*64*8);
  size_t base_used = used;
  const size_t NW_SMALL = (size_t)2*1024*1024;
  const size_t NW_BIG   = (size_t)2*4096*1024;
  size_t wbytes = (8*NW_SMALL + 2*NW_BIG)*2;
  bool pre = (base_used + wbytes + 4096) <= ws_size;

  u16 *sqWb=nullptr,*skWb=nullptr,*svWb=nullptr,*soWb=nullptr,
      *cqWb=nullptr,*ckWb=nullptr,*cvWb=nullptr,*coWb=nullptr,
      *f1Wb=nullptr,*f2Wb=nullptr;
  if (pre){
    sqWb=(u16*)alloc(NW_SMALL*2); skWb=(u16*)alloc(NW_SMALL*2);
    svWb=(u16*)alloc(NW_SMALL*2); soWb=(u16*)alloc(NW_SMALL*2);
    cqWb=(u16*)alloc(NW_SMALL*2); ckWb=(u16*)alloc(NW_SMALL*2);
    cvWb=(u16*)alloc(NW_SMALL*2); coWb=(u16*)alloc(NW_SMALL*2);
    f1Wb=(u16*)alloc(NW_BIG*2);   f2Wb=(u16*)alloc(NW_BIG*2);
  }
  const size_t PPN = (size_t)4*3072*1024;
  float* pp = nullptr;
  bool splitok = pre && (used + PPN*4 + 4096) <= ws_size;
  if (splitok) pp = (float*)alloc(PPN*4);
  const int MN = 3072*1024;

  if (pre){
    CvtArgs ca;
    const float* smallW[8] = {sqW,skW,svW,soW,cqW,ckW,cvW,coW};
    u16* smallD[8] = {sqWb,skWb,svWb,soWb,cqWb,ckWb,cvWb,coWb};
    for (int s=0; s<8; ++s){ ca.s[s] = (const float4*)smallW[s]; ca.d[s] = (ushort4*)smallD[s]; }
    for (int qd=0; qd<4; ++qd){
      ca.s[8+qd]  = (const float4*)f1W + (size_t)qd*524288;
      ca.d[8+qd]  = (ushort4*)f1Wb + (size_t)qd*524288;
      ca.s[12+qd] = (const float4*)f2W + (size_t)qd*524288;
      ca.d[12+qd] = (ushort4*)f2Wb + (size_t)qd*524288;
    }
    k_cvt_all<<<32768, 256, 0, stream>>>(ca);
  }
  k_cvt_bf16<<<512, 256, 0, stream>>>(ctx, ctxb, 131072);
  k_ada<<<3072, 256, 0, stream>>>(te, adaW, adab, mods);
  k_trig<<<768, 256, 0, stream>>>(rope, ctq, ctk);
  if (!splitok) k_copy_f32<<<3072, 256, 0, stream>>>(x_in, x, 786432);

  for (int i=0; i<2; ++i){
    const float* mi  = mods + (size_t)i*6144;
    const float* mi2 = mods + 6144;
    size_t wo = (size_t)i*1024*1024;
    size_t wof = (size_t)i*4096*1024;
    // --- self attention ---
    if (i == 0 || !splitok)
      k_ln_mod<<<3072,256,0,stream>>>(i==0 ? x_in : x, mi+0, mi+1024, hx);
    if (pre){
      k_qkv<0><<<dim3(24,24),256,0,stream>>>(hx, sqWb+wo, skWb+wo, svWb+wo, qb, kb, vt, ctq, ctk, 3072, 3072);
    } else {
      k_gemm_f32<0><<<dim3(24,8),256,0,stream>>>(hx, sqW+wo, nullptr, qb, nullptr,nullptr,nullptr, 3072,1024,1024);
      k_gemm_f32<0><<<dim3(24,8),256,0,stream>>>(hx, skW+wo, nullptr, kb, nullptr,nullptr,nullptr, 3072,1024,1024);
      k_gemm_f32<3><<<dim3(24,8),256,0,stream>>>(hx, svW+wo, nullptr, vt, nullptr,nullptr,nullptr, 3072,1024,1024);
      k_rope<<<6144,256,0,stream>>>(qb, kb, rope);
    }
    k_flash<<<dim3(48,16),256,0,stream>>>(qb, kb, vt, ob, 3072);
    if (splitok){
      k_gemm_part<<<dim3(24,8,2),256,0,stream>>>(ob, soWb+wo, pp, 3072,1024,1024,512);
      k_reduce_ln<0><<<3072,256,0,stream>>>(pp, 2, sob+(size_t)i*1024,
          (i==0 ? x_in : (const float*)x), x, mi+2048, nullptr, nullptr, hx);
    } else if (pre){
      k_gemm_bf16<2><<<dim3(24,8),256,0,stream>>>(ob, soWb+wo, sob+(size_t)i*1024, nullptr, x, x, mi+2048, 3072,1024,1024);
      k_ln_mod<<<3072,256,0,stream>>>(x, nullptr, nullptr, hx);
    } else {
      k_gemm_f32<2><<<dim3(24,8),256,0,stream>>>(ob, soW+wo, sob+(size_t)i*1024, nullptr, x, x, mi+2048, 3072,1024,1024);
      k_ln_mod<<<3072,256,0,stream>>>(x, nullptr, nullptr, hx);
    }
    // --- cross attention ---
    if (splitok){
      k_gemm_part<<<dim3(24,8,2),256,0,stream>>>(hx, cqWb+wo, pp, 3072,1024,1024,512);
      k_reduce<4><<<3072,256,0,stream>>>(pp, 2, nullptr, nullptr, nullptr, nullptr, qb, MN, 1024);
      k_kv64<<<dim3(8,32),256,0,stream>>>(ctxb, ckWb+wo, cvWb+wo, kb, vt, 512);
    } else if (pre){
      k_gemm_bf16<4><<<dim3(24,8),256,0,stream>>>(hx, cqWb+wo, nullptr, qb, nullptr,nullptr,nullptr, 3072,1024,1024);
      k_kv64<<<dim3(8,32),256,0,stream>>>(ctxb, ckWb+wo, cvWb+wo, kb, vt, 512);
    } else {
      k_gemm_f32<4><<<dim3(24,8),256,0,stream>>>(hx, cqW+wo, nullptr, qb, nullptr,nullptr,nullptr, 3072,1024,1024);
      k_gemm_f32<0><<<dim3(4,8),256,0,stream>>>(ctxb, ckW+wo, nullptr, kb, nullptr,nullptr,nullptr, 512,1024,1024);
      k_gemm_f32<3><<<dim3(4,8),256,0,stream>>>(ctxb, cvW+wo, nullptr, vt, nullptr,nullptr,nullptr, 512,1024,1024);
    }
    k_flash<<<dim3(48,16),256,0,stream>>>(qb, kb, vt, ob, 512);
    if (splitok){
      k_gemm_part<<<dim3(24,8,2),256,0,stream>>>(ob, coWb+wo, pp, 3072,1024,1024,512);
      k_reduce_ln<1><<<3072,256,0,stream>>>(pp, 2, cob+(size_t)i*1024, x, x, nullptr, mi+3072, mi+4096, hx);
    } else if (pre){
      k_gemm_bf16<2><<<dim3(24,8),256,0,stream>>>(ob, coWb+wo, cob+(size_t)i*1024, nullptr, x, x, nullptr, 3072,1024,1024);
      k_ln_mod<<<3072,256,0,stream>>>(x, mi+3072, mi+4096, hx);
    } else {
      k_gemm_f32<2><<<dim3(24,8),256,0,stream>>>(ob, coW+wo, cob+(size_t)i*1024, nullptr, x, x, nullptr, 3072,1024,1024);
      k_ln_mod<<<3072,256,0,stream>>>(x, mi+3072, mi+4096, hx);
    }
    // --- MLP ---
    if (pre){
      k_gemm_bf16<1><<<dim3(24,32),256,0,stream>>>(hx, f1Wb+wof, f1b+(size_t)i*4096, mid, nullptr,nullptr,nullptr, 3072,4096,1024);
    } else {
      k_gemm_f32<1><<<dim3(24,32),256,0,stream>>>(hx, f1W+wof, f1b+(size_t)i*4096, mid, nullptr,nullptr,nullptr, 3072,4096,1024);
    }
    if (splitok){
      k_gemm_part<<<dim3(24,8,4),256,0,stream>>>(mid, f2Wb+wof, pp, 3072,1024,4096,1024);
      if (i == 0)
        k_reduce_ln<1><<<3072,256,0,stream>>>(pp, 4, f2b, x, x, mi+5120, mi2+0, mi2+1024, hx);
      else
        k_reduce<2><<<3072,256,0,stream>>>(pp, 4, f2b+1024, x, x, mi+5120, nullptr, MN, 1024);
    } else if (pre){
      k_gemm_bf16<2><<<dim3(24,8),256,0,stream>>>(mid, f2Wb+wof, f2b+(size_t)i*1024, nullptr, x, x, mi+5120, 3072,1024,4096);
    } else {
      k_gemm_f32<2><<<dim3(24,8),256,0,stream>>>(mid, f2W+wof, f2b+(size_t)i*1024, nullptr, x, x, mi+5120, 3072,1024,4096);
    }
  }
}